// Round 1
// baseline (243.630 us; speedup 1.0000x reference)
//
#include <hip/hip_runtime.h>

typedef short bf16x8 __attribute__((ext_vector_type(8)));
typedef float f32x4 __attribute__((ext_vector_type(4)));

#define H 128
#define L 512
#define CHUNK 128
#define NCHUNK (L / CHUNK)

__device__ inline unsigned short f2bf(float x) {
  unsigned int u = __float_as_uint(x);
  u += 0x7fff + ((u >> 16) & 1);   // round-to-nearest-even
  return (unsigned short)(u >> 16);
}

// ---- prep: u = W1 @ w_seed, v = W1 @ w_node, W2 -> bf16 ----
__global__ void prep_kernel(const float* __restrict__ w_seed,
                            const float* __restrict__ w_node,
                            const float* __restrict__ W1,
                            const float* __restrict__ W2,
                            float* __restrict__ uv,
                            unsigned short* __restrict__ w2bf) {
  const int t = threadIdx.x;
  const int b = blockIdx.x;
  if (b == 0) {
    const int j = t & 127;
    const float* wv = (t < 128) ? w_seed : w_node;
    float acc = 0.f;
    for (int k = 0; k < H; ++k) acc = fmaf(W1[j * H + k], wv[k], acc);
    uv[(t < 128 ? 0 : H) + j] = acc;
  } else {
    const int idx = (b - 1) * 256 + t;
    w2bf[idx] = f2bf(W2[idx]);
  }
}

// ---- fused main kernel: one block per batch segment ----
__global__ void __launch_bounds__(256, 2) fused_kernel(
    const float* __restrict__ xs, const float* __restrict__ xn,
    const float* __restrict__ b1v, const float* __restrict__ b2v,
    const float* __restrict__ wscore, const float* __restrict__ wstop,
    const int* __restrict__ indptr, const float* __restrict__ uvec,
    const unsigned short* __restrict__ w2bf, float* __restrict__ out) {
  __shared__ __align__(16) unsigned short hbuf[2][CHUNK * H];  // 2 x 32KB
  __shared__ __align__(16) float scores_s[L];
  __shared__ float stop_s[4][H];
  __shared__ float red_s[8];
  __shared__ float s01[2];

  const int t = threadIdx.x;
  const int lane = t & 63;
  const int w = t >> 6;
  const int b = blockIdx.x;

  const int start = indptr[b * 3 + 0];
  const int mlen = indptr[b * 3 + 1] - start;
  const int clen = indptr[b * 3 + 2] - start;

  // ---- W2 fragments resident in registers (shared by role of lane) ----
  bf16x8 Bf[8][4];
  {
    const int r = lane & 15, ko = lane >> 4;
#pragma unroll
    for (int ct = 0; ct < 8; ++ct)
#pragma unroll
      for (int ks = 0; ks < 4; ++ks)
        Bf[ct][ks] = *reinterpret_cast<const bf16x8*>(
            w2bf + (ct * 16 + r) * H + (ks * 4 + ko) * 8);
  }

  // per-lane constants: h1-gen owns feature octet (t&15)
  const int koh = t & 15;
  float u8[8], v8[8], c8[8];
#pragma unroll
  for (int e = 0; e < 8; ++e) {
    u8[e] = uvec[koh * 8 + e];
    v8[e] = uvec[H + koh * 8 + e];
    c8[e] = b1v[koh * 8 + e];
  }
  // epilogue constants: lane owns column ct*16 + (lane&15)
  float wsr[8], b2r[8];
  {
    const int c0 = lane & 15;
#pragma unroll
    for (int ct = 0; ct < 8; ++ct) {
      wsr[ct] = wscore[ct * 16 + c0];
      b2r[ct] = b2v[ct * 16 + c0];
    }
  }
  float stopacc[8] = {0.f, 0.f, 0.f, 0.f, 0.f, 0.f, 0.f, 0.f};

  // generate h1 = swish(xs*u + xn*v + b1) in bf16 into swizzled LDS tile
  auto gen = [&](int c) {
    char* base = (char*)hbuf[c & 1];
    const int rb = t >> 4;
#pragma unroll
    for (int it = 0; it < 8; ++it) {
      const int r = rb + it * 16;
      const int pos = c * CHUNK + r;
      const float xsv = xs[start + pos];
      const float xnv = xn[start + pos];
      bf16x8 pk;
#pragma unroll
      for (int e = 0; e < 8; ++e) {
        float a = fmaf(xsv, u8[e], fmaf(xnv, v8[e], c8[e]));
        float sw = __fdividef(a, 1.f + __expf(-a));
        pk[e] = (short)f2bf(sw);
      }
      const int byte = (r * 256 + koh * 16) ^ ((r & 7) << 4);
      *reinterpret_cast<bf16x8*>(base + byte) = pk;
    }
  };

  // MFMA layer-2 + fused swish/score/stop epilogue
  auto mma = [&](int c) {
    const char* base = (const char*)hbuf[c & 1];
#pragma unroll
    for (int rt = 0; rt < 2; ++rt) {
      const int rbase = w * 32 + rt * 16;
      bf16x8 Af[4];
#pragma unroll
      for (int ks = 0; ks < 4; ++ks) {
        const int r = rbase + (lane & 15);
        const int byte =
            (r * 256 + (ks * 4 + (lane >> 4)) * 16) ^ ((r & 7) << 4);
        Af[ks] = *reinterpret_cast<const bf16x8*>(base + byte);
      }
      float p[4] = {0.f, 0.f, 0.f, 0.f};
      const int posb = c * CHUNK + rbase + (lane >> 4) * 4;
#pragma unroll
      for (int ct = 0; ct < 8; ++ct) {
        f32x4 acc = {0.f, 0.f, 0.f, 0.f};
#pragma unroll
        for (int ks = 0; ks < 4; ++ks)
          acc = __builtin_amdgcn_mfma_f32_16x16x32_bf16(Af[ks], Bf[ct][ks],
                                                        acc, 0, 0, 0);
#pragma unroll
        for (int reg = 0; reg < 4; ++reg) {
          const float pre = acc[reg] + b2r[ct];
          const float h2 = __fdividef(pre, 1.f + __expf(-pre));
          p[reg] = fmaf(h2, wsr[ct], p[reg]);
          stopacc[ct] += (posb + reg < mlen) ? h2 : 0.f;
        }
      }
      // lanes 0..15 of each quarter share the same 4 rows -> reduce over 16
#pragma unroll
      for (int m = 1; m < 16; m <<= 1) {
#pragma unroll
        for (int reg = 0; reg < 4; ++reg) p[reg] += __shfl_xor(p[reg], m, 64);
      }
      if ((lane & 15) == 0) {
        f32x4 sv = {p[0], p[1], p[2], p[3]};
        *reinterpret_cast<f32x4*>(&scores_s[posb]) = sv;
      }
    }
  };

  gen(0);
  __syncthreads();
#pragma unroll 1
  for (int c = 0; c < NCHUNK; ++c) {
    if (c + 1 < NCHUNK) gen(c + 1);
    mma(c);
    __syncthreads();
  }

  // ---- stop-feature reduction: cross-quarter, then cross-wave via LDS ----
#pragma unroll
  for (int ct = 0; ct < 8; ++ct) {
    float s = stopacc[ct];
    s += __shfl_xor(s, 16, 64);
    s += __shfl_xor(s, 32, 64);
    if (lane < 16) stop_s[w][ct * 16 + lane] = s;
  }
  __syncthreads();

  // ---- stop head: 2-class log-softmax (wave 0) ----
  if (w == 0) {
    const float inv = __fdividef(1.f, (float)mlen);
    const float sn0 = (stop_s[0][lane] + stop_s[1][lane] + stop_s[2][lane] +
                       stop_s[3][lane]) * inv;
    const float sn1 = (stop_s[0][lane + 64] + stop_s[1][lane + 64] +
                       stop_s[2][lane + 64] + stop_s[3][lane + 64]) * inv;
    float z0 = sn0 * wstop[lane] + sn1 * wstop[lane + 64];
    float z1 = sn0 * wstop[H + lane] + sn1 * wstop[H + lane + 64];
#pragma unroll
    for (int m = 1; m < 64; m <<= 1) {
      z0 += __shfl_xor(z0, m, 64);
      z1 += __shfl_xor(z1, m, 64);
    }
    if (lane == 0) {
      const float mx = fmaxf(z0, z1);
      const float lse = mx + __logf(__expf(z0 - mx) + __expf(z1 - mx));
      s01[0] = z0 - lse;
      s01[1] = z1 - lse;
      out[(size_t)b * (L + 1) + L] = z1 - lse;
    }
  }
  __syncthreads();

  // ---- node log-softmax over 512 scores ----
  float v0 = (t < clen) ? scores_s[t] : -__builtin_inff();
  float v1 = (t + 256 < clen) ? scores_s[t + 256] : -__builtin_inff();
  float mx = fmaxf(v0, v1);
#pragma unroll
  for (int m = 1; m < 64; m <<= 1) mx = fmaxf(mx, __shfl_xor(mx, m, 64));
  if (lane == 0) red_s[w] = mx;
  __syncthreads();
  mx = fmaxf(fmaxf(red_s[0], red_s[1]), fmaxf(red_s[2], red_s[3]));
  float sm = __expf(v0 - mx) + __expf(v1 - mx);
#pragma unroll
  for (int m = 1; m < 64; m <<= 1) sm += __shfl_xor(sm, m, 64);
  if (lane == 0) red_s[4 + w] = sm;
  __syncthreads();
  const float tot = red_s[4] + red_s[5] + red_s[6] + red_s[7];
  const float lse2 = mx + __logf(tot);
  const float addv = s01[0];
  out[(size_t)b * (L + 1) + t] = v0 - lse2 + addv;
  out[(size_t)b * (L + 1) + 256 + t] = v1 - lse2 + addv;
}

extern "C" void kernel_launch(void* const* d_in, const int* in_sizes, int n_in,
                              void* d_out, int out_size, void* d_ws,
                              size_t ws_size, hipStream_t stream) {
  const float* x_seeds = (const float*)d_in[0];
  const float* x_nodes = (const float*)d_in[1];
  const float* w_seed = (const float*)d_in[2];
  const float* w_node = (const float*)d_in[3];
  const float* W1 = (const float*)d_in[4];
  const float* b1 = (const float*)d_in[5];
  const float* W2 = (const float*)d_in[6];
  const float* b2 = (const float*)d_in[7];
  const float* w_score = (const float*)d_in[8];
  const float* W_stop = (const float*)d_in[9];
  const int* indptr = (const int*)d_in[10];

  const int B = in_sizes[10] / 3;
  float* uv = (float*)d_ws;
  unsigned short* w2bf = (unsigned short*)((char*)d_ws + 1024);

  hipLaunchKernelGGL(prep_kernel, dim3(1 + (H * H) / 256), dim3(256), 0,
                     stream, w_seed, w_node, W1, W2, uv, w2bf);
  hipLaunchKernelGGL(fused_kernel, dim3(B), dim3(256), 0, stream, x_seeds,
                     x_nodes, b1, b2, w_score, W_stop, indptr, uv, w2bf,
                     (float*)d_out);
}

// Round 2
// 183.025 us; speedup vs baseline: 1.3311x; 1.3311x over previous
//
#include <hip/hip_runtime.h>
#include <hip/hip_bf16.h>

typedef short bf16x8 __attribute__((ext_vector_type(8)));
typedef float f32x4 __attribute__((ext_vector_type(4)));

#define H 128
#define L 512
#define CHUNK 64
#define NCHUNK (L / CHUNK)

__device__ inline unsigned short f2bf(float x) {
  unsigned int u = __float_as_uint(x);
  u += 0x7fff + ((u >> 16) & 1);  // round-to-nearest-even
  return (unsigned short)(u >> 16);
}

// ---- prep: u = W1 @ w_seed, v = W1 @ w_node, W2 -> bf16 ----
__global__ void prep_kernel(const float* __restrict__ w_seed,
                            const float* __restrict__ w_node,
                            const float* __restrict__ W1,
                            const float* __restrict__ W2,
                            float* __restrict__ uv,
                            unsigned short* __restrict__ w2bf) {
  const int t = threadIdx.x;
  const int b = blockIdx.x;
  if (b == 0) {
    const int j = t & 127;
    const float* wv = (t < 128) ? w_seed : w_node;
    float acc = 0.f;
    for (int k = 0; k < H; ++k) acc = fmaf(W1[j * H + k], wv[k], acc);
    uv[(t < 128 ? 0 : H) + j] = acc;
  } else {
    const int idx = (b - 1) * 256 + t;
    w2bf[idx] = f2bf(W2[idx]);
  }
}

// ---- fused main kernel: one block per batch segment ----
// 4 waves; wave w owns output-feature columns [32w, 32w+32) of layer 2
// (so the W2 register footprint is 32 VGPR/lane, not 128).
__global__ void __launch_bounds__(256, 4) fused_kernel(
    const float* __restrict__ xs, const float* __restrict__ xn,
    const float* __restrict__ b1v, const float* __restrict__ b2v,
    const float* __restrict__ wscore, const float* __restrict__ wstop,
    const int* __restrict__ indptr, const float* __restrict__ uvec,
    const unsigned short* __restrict__ w2bf, float* __restrict__ out) {
  __shared__ __align__(16) unsigned short hbuf[2][CHUNK * H];  // 2 x 16KB
  __shared__ __align__(16) float scores_s[L];                  // 2KB
  __shared__ float stop_s[H];
  __shared__ float red_s[8];
  __shared__ float s01[2];

  const int t = threadIdx.x;
  const int lane = t & 63;
  const int w = t >> 6;
  const int b = blockIdx.x;

  const int start = indptr[b * 3 + 0];
  const int mlen = indptr[b * 3 + 1] - start;
  const int clen = indptr[b * 3 + 2] - start;

  // ---- W2 fragments in registers: wave w's 32 columns, all K ----
  bf16x8 Bf[2][4];
  const int r16 = lane & 15, ko = lane >> 4;
#pragma unroll
  for (int ct = 0; ct < 2; ++ct)
#pragma unroll
    for (int ks = 0; ks < 4; ++ks)
      Bf[ct][ks] = *reinterpret_cast<const bf16x8*>(
          w2bf + (w * 32 + ct * 16 + r16) * H + (ks * 4 + ko) * 8);

  // gen constants: thread owns feature octet (t&15)
  const int koh = t & 15;
  float u8[8], v8[8], c8[8];
#pragma unroll
  for (int e = 0; e < 8; ++e) {
    u8[e] = uvec[koh * 8 + e];
    v8[e] = uvec[H + koh * 8 + e];
    c8[e] = b1v[koh * 8 + e];
  }
  // epilogue constants: lane's column = w*32 + ct*16 + r16
  float wsr[2], b2r[2];
#pragma unroll
  for (int ct = 0; ct < 2; ++ct) {
    wsr[ct] = wscore[w * 32 + ct * 16 + r16];
    b2r[ct] = b2v[w * 32 + ct * 16 + r16];
  }
  float stopacc[2] = {0.f, 0.f};

  // zero the score accumulator (written via LDS atomics)
  scores_s[t] = 0.f;
  scores_s[t + 256] = 0.f;

  // generate h1 = swish(xs*u + xn*v + b1) in bf16 into swizzled LDS tile
  auto gen = [&](int c) {
    char* base = (char*)hbuf[c & 1];
    const int rb = t >> 4;
#pragma unroll
    for (int it = 0; it < 4; ++it) {
      const int r = rb + it * 16;
      const int pos = c * CHUNK + r;
      const float xsv = xs[start + pos];
      const float xnv = xn[start + pos];
      union {
        bf16x8 v;
        __hip_bfloat162 h2[4];
      } pk;
#pragma unroll
      for (int e = 0; e < 4; ++e) {
        const float a0 = fmaf(xsv, u8[2 * e], fmaf(xnv, v8[2 * e], c8[2 * e]));
        const float a1 =
            fmaf(xsv, u8[2 * e + 1], fmaf(xnv, v8[2 * e + 1], c8[2 * e + 1]));
        const float s0 = __fdividef(a0, 1.f + __expf(-a0));
        const float s1 = __fdividef(a1, 1.f + __expf(-a1));
        float2 f2;
        f2.x = s0;
        f2.y = s1;
        pk.h2[e] = __float22bfloat162_rn(f2);
      }
      const int byte = (r * 256 + koh * 16) ^ ((r & 7) << 4);
      *reinterpret_cast<bf16x8*>(base + byte) = pk.v;
    }
  };

  // MFMA layer-2 + fused swish/score/stop epilogue.
  // MC = 2: chunk fully inside mean window; 1: straddles; 0: outside.
  auto mma = [&](int c, auto mc_tag) {
    constexpr int MC = decltype(mc_tag)::value;
    const char* base = (const char*)hbuf[c & 1];
#pragma unroll
    for (int rt = 0; rt < 4; ++rt) {
      const int rbase = rt * 16;
      bf16x8 Af[4];
#pragma unroll
      for (int ks = 0; ks < 4; ++ks) {
        const int r = rbase + r16;
        const int byte = (r * 256 + (ks * 4 + ko) * 16) ^ ((r & 7) << 4);
        Af[ks] = *reinterpret_cast<const bf16x8*>(base + byte);
      }
      float p[4] = {0.f, 0.f, 0.f, 0.f};
      const int posb = c * CHUNK + rbase + ko * 4;
#pragma unroll
      for (int ct = 0; ct < 2; ++ct) {
        f32x4 acc = {0.f, 0.f, 0.f, 0.f};
#pragma unroll
        for (int ks = 0; ks < 4; ++ks)
          acc = __builtin_amdgcn_mfma_f32_16x16x32_bf16(Af[ks], Bf[ct][ks],
                                                        acc, 0, 0, 0);
#pragma unroll
        for (int reg = 0; reg < 4; ++reg) {
          const float pre = acc[reg] + b2r[ct];
          const float h2 = __fdividef(pre, 1.f + __expf(-pre));
          p[reg] = fmaf(h2, wsr[ct], p[reg]);
          if (MC == 2) {
            stopacc[ct] += h2;
          } else if (MC == 1) {
            stopacc[ct] += (posb + reg < mlen) ? h2 : 0.f;
          }
        }
      }
      // sum over this wave's 32 columns: ct done in-lane, 16 lanes remain
#pragma unroll
      for (int m = 1; m < 16; m <<= 1) {
#pragma unroll
        for (int reg = 0; reg < 4; ++reg) p[reg] += __shfl_xor(p[reg], m, 64);
      }
      if (r16 == 0) {
#pragma unroll
        for (int reg = 0; reg < 4; ++reg)
          atomicAdd(&scores_s[posb + reg], p[reg]);
      }
    }
  };

  gen(0);
  __syncthreads();
#pragma unroll 1
  for (int c = 0; c < NCHUNK; ++c) {
    if (c + 1 < NCHUNK) gen(c + 1);
    const int cb = c * CHUNK;
    if (cb + CHUNK <= mlen)
      mma(c, std::integral_constant<int, 2>{});
    else if (cb >= mlen)
      mma(c, std::integral_constant<int, 0>{});
    else
      mma(c, std::integral_constant<int, 1>{});
    __syncthreads();
  }

  // ---- stop-feature reduction: each wave owns its 32 columns ----
#pragma unroll
  for (int ct = 0; ct < 2; ++ct) {
    float s = stopacc[ct];
    s += __shfl_xor(s, 16, 64);
    s += __shfl_xor(s, 32, 64);
    if (lane < 16) stop_s[w * 32 + ct * 16 + lane] = s;
  }
  __syncthreads();

  // ---- stop head: 2-class log-softmax (wave 0) ----
  if (w == 0) {
    const float inv = __fdividef(1.f, (float)mlen);
    const float sn0 = stop_s[lane] * inv;
    const float sn1 = stop_s[lane + 64] * inv;
    float z0 = sn0 * wstop[lane] + sn1 * wstop[lane + 64];
    float z1 = sn0 * wstop[H + lane] + sn1 * wstop[H + lane + 64];
#pragma unroll
    for (int m = 1; m < 64; m <<= 1) {
      z0 += __shfl_xor(z0, m, 64);
      z1 += __shfl_xor(z1, m, 64);
    }
    if (lane == 0) {
      const float mx = fmaxf(z0, z1);
      const float lse = mx + __logf(__expf(z0 - mx) + __expf(z1 - mx));
      s01[0] = z0 - lse;
      s01[1] = z1 - lse;
      out[(size_t)b * (L + 1) + L] = z1 - lse;
    }
  }
  __syncthreads();

  // ---- node log-softmax over 512 scores ----
  float v0 = (t < clen) ? scores_s[t] : -__builtin_inff();
  float v1 = (t + 256 < clen) ? scores_s[t + 256] : -__builtin_inff();
  float mx = fmaxf(v0, v1);
#pragma unroll
  for (int m = 1; m < 64; m <<= 1) mx = fmaxf(mx, __shfl_xor(mx, m, 64));
  if (lane == 0) red_s[w] = mx;
  __syncthreads();
  mx = fmaxf(fmaxf(red_s[0], red_s[1]), fmaxf(red_s[2], red_s[3]));
  float sm = __expf(v0 - mx) + __expf(v1 - mx);
#pragma unroll
  for (int m = 1; m < 64; m <<= 1) sm += __shfl_xor(sm, m, 64);
  if (lane == 0) red_s[4 + w] = sm;
  __syncthreads();
  const float tot = red_s[4] + red_s[5] + red_s[6] + red_s[7];
  const float lse2 = mx + __logf(tot);
  const float addv = s01[0];
  out[(size_t)b * (L + 1) + t] = v0 - lse2 + addv;
  out[(size_t)b * (L + 1) + 256 + t] = v1 - lse2 + addv;
}

extern "C" void kernel_launch(void* const* d_in, const int* in_sizes, int n_in,
                              void* d_out, int out_size, void* d_ws,
                              size_t ws_size, hipStream_t stream) {
  const float* x_seeds = (const float*)d_in[0];
  const float* x_nodes = (const float*)d_in[1];
  const float* w_seed = (const float*)d_in[2];
  const float* w_node = (const float*)d_in[3];
  const float* W1 = (const float*)d_in[4];
  const float* b1 = (const float*)d_in[5];
  const float* W2 = (const float*)d_in[6];
  const float* b2 = (const float*)d_in[7];
  const float* w_score = (const float*)d_in[8];
  const float* W_stop = (const float*)d_in[9];
  const int* indptr = (const int*)d_in[10];

  const int B = in_sizes[10] / 3;
  float* uv = (float*)d_ws;
  unsigned short* w2bf = (unsigned short*)((char*)d_ws + 1024);

  hipLaunchKernelGGL(prep_kernel, dim3(1 + (H * H) / 256), dim3(256), 0,
                     stream, w_seed, w_node, W1, W2, uv, w2bf);
  hipLaunchKernelGGL(fused_kernel, dim3(B), dim3(256), 0, stream, x_seeds,
                     x_nodes, b1, b2, w_score, W_stop, indptr, uv, w2bf,
                     (float*)d_out);
}